// Round 9
// baseline (382.422 us; speedup 1.0000x reference)
//
#include <hip/hip_runtime.h>
#include <cstdint>
#include <cstddef>

// Problem constants
#define BATCH 4
#define SEQ   2048
#define CMOD  1024
#define NH    16
#define DH    64
#define LOG100 4.6051701859880914f
#define LOG2E  1.4426950408889634f

typedef __attribute__((ext_vector_type(8))) short bf16x8;
typedef __attribute__((ext_vector_type(4))) float f32x4;
typedef __attribute__((ext_vector_type(16))) float f32x16;

__device__ __forceinline__ float bf2f(uint16_t u) {
    union { uint32_t i; float f; } x; x.i = ((uint32_t)u) << 16; return x.f;
}
__device__ __forceinline__ float u32lo_f(uint32_t u) {
    union { uint32_t i; float f; } x; x.i = u << 16; return x.f;
}
__device__ __forceinline__ float u32hi_f(uint32_t u) {
    union { uint32_t i; float f; } x; x.i = u & 0xFFFF0000u; return x.f;
}
__device__ __forceinline__ uint16_t f2bf(float f) {
    union { float f; uint32_t i; } x; x.f = f;
    uint32_t u = x.i;
    return (uint16_t)((u + 0x7FFFu + ((u >> 16) & 1u)) >> 16);  // RNE
}
__device__ __forceinline__ float exp2_fast(float x) {
    float r; asm("v_exp_f32 %0, %1" : "=v"(r) : "v"(x)); return r;
}
__device__ __forceinline__ uint32_t cvt_pk_bf16(float lo, float hi) {
    uint32_t r;
    asm("v_cvt_pk_bf16_f32 %0, %1, %2" : "=v"(r) : "v"(lo), "v"(hi));
    return r;
}
__device__ __forceinline__ void p32swap(uint32_t& x, uint32_t& y) {
#if __has_builtin(__builtin_amdgcn_permlane32_swap)
    auto r = __builtin_amdgcn_permlane32_swap(x, y, false, false);
    x = r[0]; y = r[1];
#else
    asm volatile("v_permlane32_swap_b32 %0, %1\n\ts_nop 1" : "+v"(x), "+v"(y));
#endif
}

__device__ __forceinline__ void gload_lds16(const void* g, void* l) {
    __builtin_amdgcn_global_load_lds(
        (const __attribute__((address_space(1))) uint32_t*)g,
        (__attribute__((address_space(3))) uint32_t*)l,
        16, 0, 0);
}

// ---------------- fp32 -> bf16 convert ----------------
__global__ __launch_bounds__(256) void cvt_kernel(const float* __restrict__ in,
                                                  uint16_t* __restrict__ out, int n) {
    int i = (blockIdx.x * 256 + threadIdx.x) * 4;
    if (i >= n) return;
    float4 f = *(const float4*)(in + i);
    ushort4 o;
    o.x = f2bf(f.x); o.y = f2bf(f.y); o.z = f2bf(f.z); o.w = f2bf(f.w);
    *(ushort4*)(out + i) = o;
}

// ---------------- bf16 GEMM, B-transposed input (m97 structure) ----------------
// C[M,N] = A[M,K] * B[N,K]^T ; 128x128 tile, BK=32, 4 waves, 4x4 16x16x32 frags/wave
// mode 0: QKV epilogue -> q normalized*scale_h*log2e (bf16 [B,H,L,D]),
//         k normalized (bf16 [B,H,L,D]), v+bias pre-transposed (bf16 [B,H,D,L])
// mode 1: proj epilogue -> fp32 out + b_proj
__global__ __launch_bounds__(256) void gemm_bt_kernel(
    const uint16_t* __restrict__ A, const uint16_t* __restrict__ B,
    int M, int N, int K, int mode,
    uint16_t* __restrict__ qb, uint16_t* __restrict__ kb, uint16_t* __restrict__ vtb,
    const float* __restrict__ q_bias, const float* __restrict__ v_bias,
    const float* __restrict__ scale_mul_log,
    float* __restrict__ outp, const float* __restrict__ b_proj)
{
    __shared__ __align__(16) uint16_t As[128 * 32];
    __shared__ __align__(16) uint16_t Bs[128 * 32];
    const int t = threadIdx.x;
    const int wave = t >> 6, lane = t & 63;
    const int g = lane >> 4, c16 = lane & 15;
    const int m0 = blockIdx.x * 128, n0 = blockIdx.y * 128;
    const int wm = (wave >> 1) * 64, wn = (wave & 1) * 64;

    f32x4 acc[4][4];
#pragma unroll
    for (int mt = 0; mt < 4; mt++)
#pragma unroll
        for (int nt = 0; nt < 4; nt++) acc[mt][nt] = (f32x4){0.f, 0.f, 0.f, 0.f};

    for (int k0 = 0; k0 < K; k0 += 32) {
        __syncthreads();
#pragma unroll
        for (int i = 0; i < 2; i++) {
            int cc = i * 256 + t;           // 512 chunks of 8 elems
            int row = cc >> 2, col = (cc & 3) * 8;
            gload_lds16(A + (size_t)(m0 + row) * K + k0 + col, &As[cc * 8]);
            gload_lds16(B + (size_t)(n0 + row) * K + k0 + col, &Bs[cc * 8]);
        }
        __syncthreads();
        bf16x8 af[4], bfv[4];
#pragma unroll
        for (int mt = 0; mt < 4; mt++)
            af[mt] = *(const bf16x8*)&As[(wm + mt * 16 + c16) * 32 + g * 8];
#pragma unroll
        for (int nt = 0; nt < 4; nt++)
            bfv[nt] = *(const bf16x8*)&Bs[(wn + nt * 16 + c16) * 32 + g * 8];
#pragma unroll
        for (int mt = 0; mt < 4; mt++)
#pragma unroll
            for (int nt = 0; nt < 4; nt++)
                acc[mt][nt] = __builtin_amdgcn_mfma_f32_16x16x32_bf16(af[mt], bfv[nt], acc[mt][nt], 0, 0, 0);
    }

    if (mode == 0) {
        const int colbase = n0 + wn;          // multiple of 64 -> single (tt, head) per wave
        const int tt = colbase >> 10;
        const int cc0 = colbase & 1023;
        const int hh = cc0 >> 6;
        float qmul = 1.0f;
        if (tt == 0) qmul = __expf(fminf(scale_mul_log[hh], LOG100)) * LOG2E;
#pragma unroll
        for (int mt = 0; mt < 4; mt++) {
            float vals[4][4];
            float n2[4] = {0.f, 0.f, 0.f, 0.f};
#pragma unroll
            for (int nt = 0; nt < 4; nt++) {
                const int ci = cc0 + nt * 16 + c16;   // 0..1023 within qkv third
                float badd = 0.f;
                if (tt == 0) badd = q_bias[ci];
                else if (tt == 2) badd = v_bias[ci];
#pragma unroll
                for (int r = 0; r < 4; r++) {
                    float v = acc[mt][nt][r] + badd;
                    vals[nt][r] = v;
                    n2[r] += v * v;
                }
            }
            float rs[4];
            if (tt < 2) {   // L2-normalize q (with scale*log2e) and k over the 64-wide head dim
#pragma unroll
                for (int r = 0; r < 4; r++) {
                    float s = n2[r];
                    s += __shfl_xor(s, 1, 64);
                    s += __shfl_xor(s, 2, 64);
                    s += __shfl_xor(s, 4, 64);
                    s += __shfl_xor(s, 8, 64);
                    rs[r] = qmul / fmaxf(sqrtf(s), 1e-12f);
                }
            } else {
#pragma unroll
                for (int r = 0; r < 4; r++) rs[r] = 1.0f;
            }
#pragma unroll
            for (int nt = 0; nt < 4; nt++) {
                const int dd = (cc0 + nt * 16 + c16) & 63;
#pragma unroll
                for (int r = 0; r < 4; r++) {
                    const int row = m0 + wm + mt * 16 + g * 4 + r;   // b*2048 + l
                    const int bb = row >> 11, ll = row & 2047;
                    const size_t bhx = (size_t)bb * NH + hh;
                    const uint16_t val = f2bf(vals[nt][r] * rs[r]);
                    if (tt == 0)      qb[(bhx * SEQ + ll) * DH + dd] = val;
                    else if (tt == 1) kb[(bhx * SEQ + ll) * DH + dd] = val;
                    else              vtb[(bhx * DH + dd) * SEQ + ll] = val;  // transposed
                }
            }
        }
    } else {
#pragma unroll
        for (int mt = 0; mt < 4; mt++)
#pragma unroll
            for (int nt = 0; nt < 4; nt++)
#pragma unroll
                for (int r = 0; r < 4; r++) {
                    int row = m0 + wm + mt * 16 + g * 4 + r;
                    int col = n0 + wn + nt * 16 + c16;
                    outp[(size_t)row * N + col] = acc[mt][nt][r] + b_proj[col];
                }
    }
}

// ---------------- fused cosine-sim flash attention (coalesced-bias LDS) ----------------
// grid: 1024 blocks, gid = ((qt*16 + h)*4 + b), b innermost (bias L2/L3 sibling reuse).
// block: 4 waves on batch b; wave w owns q-rows [qt*128 + w*32, +32). KVBLK=128.
// THE FIX vs R8: bias tile [128 q][128 k] is loaded ROW-LINEARLY (each float4 instr
// = 2 rows x 512B contiguous, coalesced) into a 32KB bf16 LDS tile (x LOG2E at cvt),
// replacing 16 scattered 32-line loads per lane. Bias regs for iter t+1 are issued at
// compute start (T14) so their latency hides under compute. K/V staging as R8 (proven).
// Core: swapped mfma(K,Q) 32x32x16, static-max softmax, cvt_pk+permlane32 repack
// (all identical to R8, passed).
__global__ __launch_bounds__(256, 2) void attn_kernel(
    const uint16_t* __restrict__ qb, const uint16_t* __restrict__ kb,
    const uint16_t* __restrict__ vtb, const float* __restrict__ bias,
    uint16_t* __restrict__ ob)
{
    __shared__ __align__(16) uint16_t Ks[128 * 64];    // 16 KB, row r: chunk j at j^(r&7)
    __shared__ __align__(16) uint16_t Vs[64 * 128];    // 16 KB, row r: chunk j at j^((r&7)<<1)
    __shared__ __align__(16) uint16_t Bsh[128 * 128];  // 32 KB bf16 bias*LOG2E, [row][chunk^(row&31)]

    const int t = threadIdx.x;
    const int w = t >> 6, lane = t & 63;
    const int c32 = lane & 31, hi = lane >> 5;

    const int gid = blockIdx.x;
    const int b = gid & 3;
    const int h = (gid >> 2) & 15;
    const int qt = gid >> 6;                 // 0..15
    const size_t bh = (size_t)b * NH + h;
    const int q0 = qt * 128;                 // block q-base
    const int q0w = q0 + w * 32;             // this wave's q-base

    // Q fragments (q pre-scaled by scale_h*log2e/||q||)
    bf16x8 qf[4];
    {
        const uint16_t* qp = qb + (bh * SEQ + q0w + c32) * DH;
#pragma unroll
        for (int s = 0; s < 4; s++)
            qf[s] = *(const bf16x8*)(qp + s * 16 + hi * 8);
    }

    f32x16 accO[2];
#pragma unroll
    for (int db = 0; db < 2; db++)
#pragma unroll
        for (int i = 0; i < 16; i++) accO[db][i] = 0.f;
    float lrun = 0.f;

    // cooperative bias tile: 4096 float4 chunks; thread's chunk c = i*256+t:
    // row = c>>5 (0..127), jc = c&31 -> global [q0+row][k0 + jc*4], coalesced per row
    const float* bglob = bias + ((size_t)h * SEQ + q0) * SEQ;
    const int brow = t >> 1;                  // unused helper-free form below
    (void)brow;

    float4 breg[16];
#pragma unroll
    for (int i = 0; i < 16; i++) {
        int c = i * 256 + t, row = c >> 5, jc = c & 31;
        breg[i] = *(const float4*)(bglob + (size_t)row * SEQ + 0 + jc * 4);
    }

    for (int it = 0; it < 16; ++it) {
        const int k0 = it * 128;
        __syncthreads();   // previous tile fully consumed; LDS writable

        // convert + store bias(it): LDS[row][sj] = G[row][sj^(row&31)]
#pragma unroll
        for (int i = 0; i < 16; i++) {
            int c = i * 256 + t, row = c >> 5, jc = c & 31;
            int sj = jc ^ (row & 31);
            uint32_t u0 = cvt_pk_bf16(breg[i].x * LOG2E, breg[i].y * LOG2E);
            uint32_t u1 = cvt_pk_bf16(breg[i].z * LOG2E, breg[i].w * LOG2E);
            *reinterpret_cast<uint2*>((uint8_t*)Bsh + row * 256 + sj * 8) = make_uint2(u0, u1);
        }

        // stage K tile [128 rows][64 d]: 1024 chunks, row-linear global (contiguous)
#pragma unroll
        for (int i = 0; i < 4; i++) {
            int c = i * 256 + t;
            int row = c >> 3, jc = c & 7, sj = jc ^ (row & 7);
            gload_lds16(kb + (bh * SEQ + k0 + row) * DH + sj * 8, &Ks[c * 8]);
        }
        // stage V^T tile [64 d-rows][128 k]: 1024 chunks (256B contiguous per row)
#pragma unroll
        for (int i = 0; i < 4; i++) {
            int c = i * 256 + t;
            int row = c >> 4, jc = c & 15, sj = jc ^ ((row & 7) << 1);
            gload_lds16(vtb + (bh * DH + row) * SEQ + k0 + sj * 8, &Vs[c * 8]);
        }
        __syncthreads();   // staging drained (DMA + bias ds_writes)

        // T14: issue next iter's bias loads now -> latency hidden under compute
        if (it + 1 < 16) {
            const float* bnext = bglob + (it + 1) * 128;
#pragma unroll
            for (int i = 0; i < 16; i++) {
                int c = i * 256 + t, row = c >> 5, jc = c & 31;
                breg[i] = *(const float4*)(bnext + (size_t)row * SEQ + jc * 4);
            }
        }

#pragma unroll
        for (int kb2 = 0; kb2 < 4; kb2++) {
            // S^T = K Q^T : reg r -> k_local = kb2*32 + (r&3)+8*(r>>2)+4*hi ; q-row = c32
            f32x16 S;
#pragma unroll
            for (int i = 0; i < 16; i++) S[i] = 0.f;
#pragma unroll
            for (int s = 0; s < 4; s++) {
                int row = kb2 * 32 + c32;
                int jc = 2 * s + hi;
                bf16x8 kf = *(const bf16x8*)&Ks[(row * 8 + (jc ^ (row & 7))) * 8];
                S = __builtin_amdgcn_mfma_f32_32x32x16_bf16(kf, qf[s], S, 0, 0, 0);
            }

            // softmax (static max): p = exp2(S + bias*log2e), bias from LDS (bf16)
            float p[16];
            float lp = 0.f;
            const int myrow = w * 32 + c32;
#pragma unroll
            for (int tt = 0; tt < 4; tt++) {
                int jc = kb2 * 8 + tt * 2 + hi;
                uint2 uu = *reinterpret_cast<const uint2*>(
                    (const uint8_t*)Bsh + myrow * 256 + (jc ^ c32) * 8);
                p[tt * 4 + 0] = exp2_fast(S[tt * 4 + 0] + u32lo_f(uu.x));
                p[tt * 4 + 1] = exp2_fast(S[tt * 4 + 1] + u32hi_f(uu.x));
                p[tt * 4 + 2] = exp2_fast(S[tt * 4 + 2] + u32lo_f(uu.y));
                p[tt * 4 + 3] = exp2_fast(S[tt * 4 + 3] + u32hi_f(uu.y));
                lp += (p[tt * 4 + 0] + p[tt * 4 + 1]) + (p[tt * 4 + 2] + p[tt * 4 + 3]);
            }
            lrun += lp;

            // m214 repack -> PV A-fragments for this 32-k block
            bf16x8 pa[2];
#pragma unroll
            for (int cp = 0; cp < 2; cp++) {
                uint32_t X0 = cvt_pk_bf16(p[8 * cp + 0], p[8 * cp + 1]);
                uint32_t X1 = cvt_pk_bf16(p[8 * cp + 2], p[8 * cp + 3]);
                uint32_t Y0 = cvt_pk_bf16(p[8 * cp + 4], p[8 * cp + 5]);
                uint32_t Y1 = cvt_pk_bf16(p[8 * cp + 6], p[8 * cp + 7]);
                p32swap(X0, Y0);
                p32swap(X1, Y1);
                union { uint32_t u[4]; bf16x8 v; } pu;
                pu.u[0] = X0; pu.u[1] = X1; pu.u[2] = Y0; pu.u[3] = Y1;
                pa[cp] = pu.v;
            }

            // O += P V for this 32-k block
#pragma unroll
            for (int c = 0; c < 2; c++)
#pragma unroll
                for (int db = 0; db < 2; db++) {
                    int vrow = db * 32 + c32;
                    int vjc = kb2 * 4 + 2 * c + hi;
                    bf16x8 vf = *(const bf16x8*)&Vs[(vrow * 16 + (vjc ^ ((vrow & 7) << 1))) * 8];
                    accO[db] = __builtin_amdgcn_mfma_f32_32x32x16_bf16(pa[c], vf, accO[db], 0, 0, 0);
                }
        }
    }

    // finalize: row-sum reduce + redistribute, O /= l, write bf16 [B, L, H*D]
    float s = lrun + __shfl_xor(lrun, 32, 64);
    float inv = 1.0f / s;                     // valid for q-row = c32 on all lanes
    float linv[16];
#pragma unroll
    for (int r = 0; r < 16; r++)
        linv[r] = __shfl(inv, (r & 3) + 8 * (r >> 2) + 4 * hi, 64);
#pragma unroll
    for (int r = 0; r < 16; r++) {
        int rowq = (r & 3) + 8 * (r >> 2) + 4 * hi;
        size_t rowbase = ((size_t)b * SEQ + q0w + rowq) * CMOD + h * DH;
        ob[rowbase + c32]      = f2bf(accO[0][r] * linv[r]);
        ob[rowbase + 32 + c32] = f2bf(accO[1][r] * linv[r]);
    }
}

// ---------------- launch ----------------
extern "C" void kernel_launch(void* const* d_in, const int* in_sizes, int n_in,
                              void* d_out, int out_size, void* d_ws, size_t ws_size,
                              hipStream_t stream) {
    const float* x             = (const float*)d_in[0];
    const float* attn_bias     = (const float*)d_in[1];
    const float* W_qkv         = (const float*)d_in[2];
    const float* q_bias        = (const float*)d_in[3];
    const float* v_bias        = (const float*)d_in[4];
    const float* scale_mul_log = (const float*)d_in[5];
    const float* W_proj        = (const float*)d_in[6];
    const float* b_proj        = (const float*)d_in[7];
    float* out = (float*)d_out;

    uint8_t* ws = (uint8_t*)d_ws;
    size_t off = 0;
    auto alloc = [&](size_t bytes) { uint8_t* p = ws + off; off += (bytes + 255) & ~(size_t)255; return p; };
    uint16_t* xb     = (uint16_t*)alloc((size_t)8192 * 1024 * 2);
    uint16_t* wqkvb  = (uint16_t*)alloc((size_t)3072 * 1024 * 2);
    uint16_t* wprojb = (uint16_t*)alloc((size_t)1024 * 1024 * 2);
    uint16_t* qb     = (uint16_t*)alloc((size_t)BATCH * NH * SEQ * DH * 2);
    uint16_t* kb     = (uint16_t*)alloc((size_t)BATCH * NH * SEQ * DH * 2);
    uint16_t* vtb    = (uint16_t*)alloc((size_t)BATCH * NH * SEQ * DH * 2);
    uint16_t* ob     = (uint16_t*)alloc((size_t)BATCH * SEQ * CMOD * 2);
    (void)ws_size;

    cvt_kernel<<<8192, 256, 0, stream>>>(x, xb, 8388608);
    cvt_kernel<<<3072, 256, 0, stream>>>(W_qkv, wqkvb, 3145728);
    cvt_kernel<<<1024, 256, 0, stream>>>(W_proj, wprojb, 1048576);

    dim3 g1(64, 24);
    gemm_bt_kernel<<<g1, 256, 0, stream>>>(xb, wqkvb, 8192, 3072, 1024, 0,
                                           qb, kb, vtb, q_bias, v_bias, scale_mul_log,
                                           nullptr, nullptr);

    attn_kernel<<<1024, 256, 0, stream>>>(qb, kb, vtb, attn_bias, ob);

    dim3 g3(64, 8);
    gemm_bt_kernel<<<g3, 256, 0, stream>>>(ob, wprojb, 8192, 1024, 1024, 1,
                                           nullptr, nullptr, nullptr, nullptr, nullptr, nullptr,
                                           out, b_proj);
}

// Round 10
// 316.506 us; speedup vs baseline: 1.2083x; 1.2083x over previous
//
#include <hip/hip_runtime.h>
#include <cstdint>
#include <cstddef>

// Problem constants
#define BATCH 4
#define SEQ   2048
#define CMOD  1024
#define NH    16
#define DH    64
#define LOG100 4.6051701859880914f
#define LOG2E  1.4426950408889634f

typedef __attribute__((ext_vector_type(8))) short bf16x8;
typedef __attribute__((ext_vector_type(4))) float f32x4;
typedef __attribute__((ext_vector_type(16))) float f32x16;

__device__ __forceinline__ float bf2f(uint16_t u) {
    union { uint32_t i; float f; } x; x.i = ((uint32_t)u) << 16; return x.f;
}
__device__ __forceinline__ uint16_t f2bf(float f) {
    union { float f; uint32_t i; } x; x.f = f;
    uint32_t u = x.i;
    return (uint16_t)((u + 0x7FFFu + ((u >> 16) & 1u)) >> 16);  // RNE
}
__device__ __forceinline__ float exp2_fast(float x) {
    float r; asm("v_exp_f32 %0, %1" : "=v"(r) : "v"(x)); return r;
}
__device__ __forceinline__ uint32_t cvt_pk_bf16(float lo, float hi) {
    uint32_t r;
    asm("v_cvt_pk_bf16_f32 %0, %1, %2" : "=v"(r) : "v"(lo), "v"(hi));
    return r;
}
__device__ __forceinline__ void p32swap(uint32_t& x, uint32_t& y) {
#if __has_builtin(__builtin_amdgcn_permlane32_swap)
    auto r = __builtin_amdgcn_permlane32_swap(x, y, false, false);
    x = r[0]; y = r[1];
#else
    asm volatile("v_permlane32_swap_b32 %0, %1\n\ts_nop 1" : "+v"(x), "+v"(y));
#endif
}

__device__ __forceinline__ void gload_lds16(const void* g, void* l) {
    __builtin_amdgcn_global_load_lds(
        (const __attribute__((address_space(1))) uint32_t*)g,
        (__attribute__((address_space(3))) uint32_t*)l,
        16, 0, 0);
}

// ---------------- fp32 -> bf16 convert ----------------
__global__ __launch_bounds__(256) void cvt_kernel(const float* __restrict__ in,
                                                  uint16_t* __restrict__ out, int n) {
    int i = (blockIdx.x * 256 + threadIdx.x) * 4;
    if (i >= n) return;
    float4 f = *(const float4*)(in + i);
    ushort4 o;
    o.x = f2bf(f.x); o.y = f2bf(f.y); o.z = f2bf(f.z); o.w = f2bf(f.w);
    *(ushort4*)(out + i) = o;
}

// ---------------- bf16 GEMM, B-transposed input (m97 structure) ----------------
// C[M,N] = A[M,K] * B[N,K]^T ; 128x128 tile, BK=32, 4 waves, 4x4 16x16x32 frags/wave
// mode 0: QKV epilogue -> q normalized*scale_h*log2e (bf16 [B,H,L,D]),
//         k normalized (bf16 [B,H,L,D]), v+bias pre-transposed (bf16 [B,H,D,L])
// mode 1: proj epilogue -> fp32 out + b_proj
__global__ __launch_bounds__(256) void gemm_bt_kernel(
    const uint16_t* __restrict__ A, const uint16_t* __restrict__ B,
    int M, int N, int K, int mode,
    uint16_t* __restrict__ qb, uint16_t* __restrict__ kb, uint16_t* __restrict__ vtb,
    const float* __restrict__ q_bias, const float* __restrict__ v_bias,
    const float* __restrict__ scale_mul_log,
    float* __restrict__ outp, const float* __restrict__ b_proj)
{
    __shared__ __align__(16) uint16_t As[128 * 32];
    __shared__ __align__(16) uint16_t Bs[128 * 32];
    const int t = threadIdx.x;
    const int wave = t >> 6, lane = t & 63;
    const int g = lane >> 4, c16 = lane & 15;
    const int m0 = blockIdx.x * 128, n0 = blockIdx.y * 128;
    const int wm = (wave >> 1) * 64, wn = (wave & 1) * 64;

    f32x4 acc[4][4];
#pragma unroll
    for (int mt = 0; mt < 4; mt++)
#pragma unroll
        for (int nt = 0; nt < 4; nt++) acc[mt][nt] = (f32x4){0.f, 0.f, 0.f, 0.f};

    for (int k0 = 0; k0 < K; k0 += 32) {
        __syncthreads();
#pragma unroll
        for (int i = 0; i < 2; i++) {
            int cc = i * 256 + t;           // 512 chunks of 8 elems
            int row = cc >> 2, col = (cc & 3) * 8;
            gload_lds16(A + (size_t)(m0 + row) * K + k0 + col, &As[cc * 8]);
            gload_lds16(B + (size_t)(n0 + row) * K + k0 + col, &Bs[cc * 8]);
        }
        __syncthreads();
        bf16x8 af[4], bfv[4];
#pragma unroll
        for (int mt = 0; mt < 4; mt++)
            af[mt] = *(const bf16x8*)&As[(wm + mt * 16 + c16) * 32 + g * 8];
#pragma unroll
        for (int nt = 0; nt < 4; nt++)
            bfv[nt] = *(const bf16x8*)&Bs[(wn + nt * 16 + c16) * 32 + g * 8];
#pragma unroll
        for (int mt = 0; mt < 4; mt++)
#pragma unroll
            for (int nt = 0; nt < 4; nt++)
                acc[mt][nt] = __builtin_amdgcn_mfma_f32_16x16x32_bf16(af[mt], bfv[nt], acc[mt][nt], 0, 0, 0);
    }

    if (mode == 0) {
        const int colbase = n0 + wn;          // multiple of 64 -> single (tt, head) per wave
        const int tt = colbase >> 10;
        const int cc0 = colbase & 1023;
        const int hh = cc0 >> 6;
        float qmul = 1.0f;
        if (tt == 0) qmul = __expf(fminf(scale_mul_log[hh], LOG100)) * LOG2E;
#pragma unroll
        for (int mt = 0; mt < 4; mt++) {
            float vals[4][4];
            float n2[4] = {0.f, 0.f, 0.f, 0.f};
#pragma unroll
            for (int nt = 0; nt < 4; nt++) {
                const int ci = cc0 + nt * 16 + c16;   // 0..1023 within qkv third
                float badd = 0.f;
                if (tt == 0) badd = q_bias[ci];
                else if (tt == 2) badd = v_bias[ci];
#pragma unroll
                for (int r = 0; r < 4; r++) {
                    float v = acc[mt][nt][r] + badd;
                    vals[nt][r] = v;
                    n2[r] += v * v;
                }
            }
            float rs[4];
            if (tt < 2) {   // L2-normalize q (with scale*log2e) and k over the 64-wide head dim
#pragma unroll
                for (int r = 0; r < 4; r++) {
                    float s = n2[r];
                    s += __shfl_xor(s, 1, 64);
                    s += __shfl_xor(s, 2, 64);
                    s += __shfl_xor(s, 4, 64);
                    s += __shfl_xor(s, 8, 64);
                    rs[r] = qmul / fmaxf(sqrtf(s), 1e-12f);
                }
            } else {
#pragma unroll
                for (int r = 0; r < 4; r++) rs[r] = 1.0f;
            }
#pragma unroll
            for (int nt = 0; nt < 4; nt++) {
                const int dd = (cc0 + nt * 16 + c16) & 63;
#pragma unroll
                for (int r = 0; r < 4; r++) {
                    const int row = m0 + wm + mt * 16 + g * 4 + r;   // b*2048 + l
                    const int bb = row >> 11, ll = row & 2047;
                    const size_t bhx = (size_t)bb * NH + hh;
                    const uint16_t val = f2bf(vals[nt][r] * rs[r]);
                    if (tt == 0)      qb[(bhx * SEQ + ll) * DH + dd] = val;
                    else if (tt == 1) kb[(bhx * SEQ + ll) * DH + dd] = val;
                    else              vtb[(bhx * DH + dd) * SEQ + ll] = val;  // transposed
                }
            }
        }
    } else {
#pragma unroll
        for (int mt = 0; mt < 4; mt++)
#pragma unroll
            for (int nt = 0; nt < 4; nt++)
#pragma unroll
                for (int r = 0; r < 4; r++) {
                    int row = m0 + wm + mt * 16 + g * 4 + r;
                    int col = n0 + wn + nt * 16 + c16;
                    outp[(size_t)row * N + col] = acc[mt][nt][r] + b_proj[col];
                }
    }
}

// ---------------- fused cosine-sim flash attention (batch-in-block + coalesced bias) ----------------
// grid: 1024 blocks, gid = h*64 + qt ; block: 4 waves, wave w = batch w, QBLK=32, KVBLK=64.
// BIAS IS STRUCTURALLY DEDUPED: one [32 q][64 k] f32 tile per block-iter, loaded
// row-linearly (256B bursts), x LOG2E, ds_write'd to LDS; all 4 waves (batches) read it
// -> bias HBM traffic = 256 MB exactly, no reliance on inter-block cache timing (R9's 657MB bug).
// Bias regs for iter t+1 issued at compute start (T14) -> drain covered by compute.
// K/V staged per batch via R2-proven pattern (row-XOR chunks, gload_lds, contiguous global).
// Core: swapped mfma(K,Q) 32x32x16 (m74/m101 layout), static-max softmax,
// cvt_pk + permlane32_swap repack (m214-v22) — verbatim from R9 (passed).
__global__ __launch_bounds__(256, 2) void attn_kernel(
    const uint16_t* __restrict__ qb, const uint16_t* __restrict__ kb,
    const uint16_t* __restrict__ vtb, const float* __restrict__ bias,
    uint16_t* __restrict__ ob)
{
    __shared__ __align__(16) uint16_t Ks[4][64 * 64];  // per-batch [krow][8 ch], ch^(row&7) — 32 KB
    __shared__ __align__(16) uint16_t Vs[4][64 * 64];  // per-batch [d][8 ch], ch^(row&7)   — 32 KB
    __shared__ __align__(16) float    Bsh[32 * 64];    // [qrow][16 ch], ch^((row&7)<<1)    —  8 KB

    const int t = threadIdx.x;
    const int w = t >> 6, lane = t & 63;       // wave index == batch index
    const int c32 = lane & 31, hi = lane >> 5;

    const int h = blockIdx.x >> 6;             // 0..15
    const int qt = blockIdx.x & 63;            // 0..63
    const int q0 = qt * 32;
    const size_t bh = (size_t)w * NH + h;

    // Q fragments (q pre-scaled by scale_h*log2e/||q||)
    bf16x8 qf[4];
    {
        const uint16_t* qp = qb + (bh * SEQ + q0 + c32) * DH;
#pragma unroll
        for (int s = 0; s < 4; s++)
            qf[s] = *(const bf16x8*)(qp + s * 16 + hi * 8);
    }

    f32x16 accO[2];
#pragma unroll
    for (int db = 0; db < 2; db++)
#pragma unroll
        for (int i = 0; i < 16; i++) accO[db][i] = 0.f;
    float lrun = 0.f;

    // bias cooperative load: thread t -> row = t>>3 (0..31), ch = t&7; 2 float4 = [row][ch*8..+8)
    const int brow = t >> 3, bch = t & 7;
    const float* bgl = bias + ((size_t)h * SEQ + q0 + brow) * SEQ + bch * 8;
    float4 br0 = *(const float4*)(bgl);
    float4 br1 = *(const float4*)(bgl + 4);

    for (int it = 0; it < 32; ++it) {
        const int k0 = it * 64;
        __syncthreads();   // A: previous tile fully consumed, LDS writable

        // bias(cur): x LOG2E, swizzled ds_write (chunk u = bch*2+{0,1}, u' = u^((row&7)<<1))
        {
            const int sw = (brow & 7) << 1;
            float4 w0, w1;
            w0.x = br0.x * LOG2E; w0.y = br0.y * LOG2E; w0.z = br0.z * LOG2E; w0.w = br0.w * LOG2E;
            w1.x = br1.x * LOG2E; w1.y = br1.y * LOG2E; w1.z = br1.z * LOG2E; w1.w = br1.w * LOG2E;
            *reinterpret_cast<float4*>(&Bsh[brow * 64 + ((bch * 2) ^ sw) * 4])     = w0;
            *reinterpret_cast<float4*>(&Bsh[brow * 64 + ((bch * 2 + 1) ^ sw) * 4]) = w1;
        }

        // stage K and V^T for all 4 batches (R2-proven pattern; K global reads contiguous)
#pragma unroll
        for (int i = 0; i < 8; i++) {
            int c = i * 256 + t;               // 0..2047
            int bw = c >> 9, cc = c & 511;
            int row = cc >> 3, jc = cc & 7, sj = jc ^ (row & 7);
            gload_lds16(kb + (((size_t)bw * NH + h) * SEQ + k0 + row) * DH + sj * 8, &Ks[bw][cc * 8]);
            gload_lds16(vtb + (((size_t)bw * NH + h) * DH + row) * SEQ + k0 + sj * 8, &Vs[bw][cc * 8]);
        }
        __syncthreads();   // B: staging + bias writes visible

        // T14: issue next iter's bias regs now -> latency hidden under compute
        if (it + 1 < 32) {
            br0 = *(const float4*)(bgl + (it + 1) * 64);
            br1 = *(const float4*)(bgl + (it + 1) * 64 + 4);
        }

#pragma unroll
        for (int kb2 = 0; kb2 < 2; kb2++) {
            // S^T = K Q^T : reg r -> k_local = kb2*32 + (r&3)+8*(r>>2)+4*hi ; q-row = c32
            f32x16 S;
#pragma unroll
            for (int i = 0; i < 16; i++) S[i] = 0.f;
#pragma unroll
            for (int s = 0; s < 4; s++) {
                int krow = kb2 * 32 + c32;
                int ku = (2 * s + hi) ^ (krow & 7);
                bf16x8 kf = *(const bf16x8*)&Ks[w][(krow * 8 + ku) * 8];
                S = __builtin_amdgcn_mfma_f32_32x32x16_bf16(kf, qf[s], S, 0, 0, 0);
            }

            // softmax (static max): p = exp2(S + bias*log2e), bias*log2e from LDS f32
            float p[16];
            float lp = 0.f;
#pragma unroll
            for (int tt = 0; tt < 4; tt++) {
                int u = kb2 * 8 + tt * 2 + hi;
                int up = u ^ ((c32 & 7) << 1);
                float4 bl = *reinterpret_cast<const float4*>(&Bsh[c32 * 64 + up * 4]);
                p[tt * 4 + 0] = exp2_fast(S[tt * 4 + 0] + bl.x);
                p[tt * 4 + 1] = exp2_fast(S[tt * 4 + 1] + bl.y);
                p[tt * 4 + 2] = exp2_fast(S[tt * 4 + 2] + bl.z);
                p[tt * 4 + 3] = exp2_fast(S[tt * 4 + 3] + bl.w);
                lp += (p[tt * 4 + 0] + p[tt * 4 + 1]) + (p[tt * 4 + 2] + p[tt * 4 + 3]);
            }
            lrun += lp;

            // m214 repack -> PV A-fragments for this 32-k block
            bf16x8 pa[2];
#pragma unroll
            for (int cp = 0; cp < 2; cp++) {
                uint32_t X0 = cvt_pk_bf16(p[8 * cp + 0], p[8 * cp + 1]);
                uint32_t X1 = cvt_pk_bf16(p[8 * cp + 2], p[8 * cp + 3]);
                uint32_t Y0 = cvt_pk_bf16(p[8 * cp + 4], p[8 * cp + 5]);
                uint32_t Y1 = cvt_pk_bf16(p[8 * cp + 6], p[8 * cp + 7]);
                p32swap(X0, Y0);
                p32swap(X1, Y1);
                union { uint32_t u[4]; bf16x8 v; } pu;
                pu.u[0] = X0; pu.u[1] = X1; pu.u[2] = Y0; pu.u[3] = Y1;
                pa[cp] = pu.v;
            }

            // O += P V for this 32-k block
#pragma unroll
            for (int c = 0; c < 2; c++)
#pragma unroll
                for (int db = 0; db < 2; db++) {
                    int vrow = db * 32 + c32;
                    int vu = (kb2 * 4 + 2 * c + hi) ^ (vrow & 7);
                    bf16x8 vf = *(const bf16x8*)&Vs[w][(vrow * 8 + vu) * 8];
                    accO[db] = __builtin_amdgcn_mfma_f32_32x32x16_bf16(pa[c], vf, accO[db], 0, 0, 0);
                }
        }
    }

    // finalize: row-sum reduce + redistribute, O /= l, write bf16 [B, L, H*D]
    float s = lrun + __shfl_xor(lrun, 32, 64);
    float inv = 1.0f / s;                     // valid for q-row = c32 on all lanes
    float linv[16];
#pragma unroll
    for (int r = 0; r < 16; r++)
        linv[r] = __shfl(inv, (r & 3) + 8 * (r >> 2) + 4 * hi, 64);
#pragma unroll
    for (int r = 0; r < 16; r++) {
        int rowq = (r & 3) + 8 * (r >> 2) + 4 * hi;
        size_t rowbase = ((size_t)w * SEQ + q0 + rowq) * CMOD + h * DH;
        ob[rowbase + c32]      = f2bf(accO[0][r] * linv[r]);
        ob[rowbase + 32 + c32] = f2bf(accO[1][r] * linv[r]);
    }
}

// ---------------- launch ----------------
extern "C" void kernel_launch(void* const* d_in, const int* in_sizes, int n_in,
                              void* d_out, int out_size, void* d_ws, size_t ws_size,
                              hipStream_t stream) {
    const float* x             = (const float*)d_in[0];
    const float* attn_bias     = (const float*)d_in[1];
    const float* W_qkv         = (const float*)d_in[2];
    const float* q_bias        = (const float*)d_in[3];
    const float* v_bias        = (const float*)d_in[4];
    const float* scale_mul_log = (const float*)d_in[5];
    const float* W_proj        = (const float*)d_in[6];
    const float* b_proj        = (const float*)d_in[7];
    float* out = (float*)d_out;

    uint8_t* ws = (uint8_t*)d_ws;
    size_t off = 0;
    auto alloc = [&](size_t bytes) { uint8_t* p = ws + off; off += (bytes + 255) & ~(size_t)255; return p; };
    uint16_t* xb     = (uint16_t*)alloc((size_t)8192 * 1024 * 2);
    uint16_t* wqkvb  = (uint16_t*)alloc((size_t)3072 * 1024 * 2);
    uint16_t* wprojb = (uint16_t*)alloc((size_t)1024 * 1024 * 2);
    uint16_t* qb     = (uint16_t*)alloc((size_t)BATCH * NH * SEQ * DH * 2);
    uint16_t* kb     = (uint16_t*)alloc((size_t)BATCH * NH * SEQ * DH * 2);
    uint16_t* vtb    = (uint16_t*)alloc((size_t)BATCH * NH * SEQ * DH * 2);
    uint16_t* ob     = (uint16_t*)alloc((size_t)BATCH * SEQ * CMOD * 2);
    (void)ws_size;

    cvt_kernel<<<8192, 256, 0, stream>>>(x, xb, 8388608);
    cvt_kernel<<<3072, 256, 0, stream>>>(W_qkv, wqkvb, 3145728);
    cvt_kernel<<<1024, 256, 0, stream>>>(W_proj, wprojb, 1048576);

    dim3 g1(64, 24);
    gemm_bt_kernel<<<g1, 256, 0, stream>>>(xb, wqkvb, 8192, 3072, 1024, 0,
                                           qb, kb, vtb, q_bias, v_bias, scale_mul_log,
                                           nullptr, nullptr);

    attn_kernel<<<1024, 256, 0, stream>>>(qb, kb, vtb, attn_bias, ob);

    dim3 g3(64, 8);
    gemm_bt_kernel<<<g3, 256, 0, stream>>>(ob, wprojb, 8192, 1024, 1024, 1,
                                           nullptr, nullptr, nullptr, nullptr, nullptr, nullptr,
                                           out, b_proj);
}

// Round 11
// 296.233 us; speedup vs baseline: 1.2909x; 1.0684x over previous
//
#include <hip/hip_runtime.h>
#include <cstdint>
#include <cstddef>

// Problem constants
#define BATCH 4
#define SEQ   2048
#define CMOD  1024
#define NH    16
#define DH    64
#define LOG100 4.6051701859880914f
#define LOG2E  1.4426950408889634f

typedef __attribute__((ext_vector_type(8))) short bf16x8;
typedef __attribute__((ext_vector_type(4))) float f32x4;
typedef __attribute__((ext_vector_type(16))) float f32x16;

__device__ __forceinline__ float u32lo_f(uint32_t u) {
    union { uint32_t i; float f; } x; x.i = u << 16; return x.f;
}
__device__ __forceinline__ float u32hi_f(uint32_t u) {
    union { uint32_t i; float f; } x; x.i = u & 0xFFFF0000u; return x.f;
}
__device__ __forceinline__ uint16_t f2bf(float f) {
    union { float f; uint32_t i; } x; x.f = f;
    uint32_t u = x.i;
    return (uint16_t)((u + 0x7FFFu + ((u >> 16) & 1u)) >> 16);  // RNE
}
__device__ __forceinline__ float exp2_fast(float x) {
    float r; asm("v_exp_f32 %0, %1" : "=v"(r) : "v"(x)); return r;
}
__device__ __forceinline__ uint32_t cvt_pk_bf16(float lo, float hi) {
    uint32_t r;
    asm("v_cvt_pk_bf16_f32 %0, %1, %2" : "=v"(r) : "v"(lo), "v"(hi));
    return r;
}
__device__ __forceinline__ void p32swap(uint32_t& x, uint32_t& y) {
#if __has_builtin(__builtin_amdgcn_permlane32_swap)
    auto r = __builtin_amdgcn_permlane32_swap(x, y, false, false);
    x = r[0]; y = r[1];
#else
    asm volatile("v_permlane32_swap_b32 %0, %1\n\ts_nop 1" : "+v"(x), "+v"(y));
#endif
}

__device__ __forceinline__ void gload_lds16(const void* g, void* l) {
    __builtin_amdgcn_global_load_lds(
        (const __attribute__((address_space(1))) uint32_t*)g,
        (__attribute__((address_space(3))) uint32_t*)l,
        16, 0, 0);
}

// ---------------- fp32 -> bf16 convert ----------------
__global__ __launch_bounds__(256) void cvt_kernel(const float* __restrict__ in,
                                                  uint16_t* __restrict__ out, int n) {
    int i = (blockIdx.x * 256 + threadIdx.x) * 4;
    if (i >= n) return;
    float4 f = *(const float4*)(in + i);
    ushort4 o;
    o.x = f2bf(f.x); o.y = f2bf(f.y); o.z = f2bf(f.z); o.w = f2bf(f.w);
    *(ushort4*)(out + i) = o;
}

// ---------------- bf16 GEMM, B-transposed input (m97 structure) ----------------
// mode 0: QKV epilogue. q/k normalized (q also * scale_h*log2e), then written in
// MFMA-FRAGMENT ORDER so attention can stage with lane-linear gload_lds:
//   q/k: addr = ((bh*64 + (l>>5))*4 + (d>>4))*512 + ((d>>3)&1)*256 + (l&31)*8 + (d&7)
//   v  : addr = ((bh*64 + (l>>5))*4 + (d>>5)*2 + ((l>>4)&1))*512
//               + (((l>>3)&1)*32 + (d&31))*8 + (l&7)
// mode 1: proj epilogue -> fp32 out + b_proj (unchanged).
__global__ __launch_bounds__(256) void gemm_bt_kernel(
    const uint16_t* __restrict__ A, const uint16_t* __restrict__ B,
    int M, int N, int K, int mode,
    uint16_t* __restrict__ qb, uint16_t* __restrict__ kb, uint16_t* __restrict__ vtb,
    const float* __restrict__ q_bias, const float* __restrict__ v_bias,
    const float* __restrict__ scale_mul_log,
    float* __restrict__ outp, const float* __restrict__ b_proj)
{
    __shared__ __align__(16) uint16_t As[128 * 32];
    __shared__ __align__(16) uint16_t Bs[128 * 32];
    const int t = threadIdx.x;
    const int wave = t >> 6, lane = t & 63;
    const int g = lane >> 4, c16 = lane & 15;
    const int m0 = blockIdx.x * 128, n0 = blockIdx.y * 128;
    const int wm = (wave >> 1) * 64, wn = (wave & 1) * 64;

    f32x4 acc[4][4];
#pragma unroll
    for (int mt = 0; mt < 4; mt++)
#pragma unroll
        for (int nt = 0; nt < 4; nt++) acc[mt][nt] = (f32x4){0.f, 0.f, 0.f, 0.f};

    for (int k0 = 0; k0 < K; k0 += 32) {
        __syncthreads();
#pragma unroll
        for (int i = 0; i < 2; i++) {
            int cc = i * 256 + t;           // 512 chunks of 8 elems
            int row = cc >> 2, col = (cc & 3) * 8;
            gload_lds16(A + (size_t)(m0 + row) * K + k0 + col, &As[cc * 8]);
            gload_lds16(B + (size_t)(n0 + row) * K + k0 + col, &Bs[cc * 8]);
        }
        __syncthreads();
        bf16x8 af[4], bfv[4];
#pragma unroll
        for (int mt = 0; mt < 4; mt++)
            af[mt] = *(const bf16x8*)&As[(wm + mt * 16 + c16) * 32 + g * 8];
#pragma unroll
        for (int nt = 0; nt < 4; nt++)
            bfv[nt] = *(const bf16x8*)&Bs[(wn + nt * 16 + c16) * 32 + g * 8];
#pragma unroll
        for (int mt = 0; mt < 4; mt++)
#pragma unroll
            for (int nt = 0; nt < 4; nt++)
                acc[mt][nt] = __builtin_amdgcn_mfma_f32_16x16x32_bf16(af[mt], bfv[nt], acc[mt][nt], 0, 0, 0);
    }

    if (mode == 0) {
        const int colbase = n0 + wn;          // multiple of 64 -> single (tt, head) per wave
        const int tt = colbase >> 10;
        const int cc0 = colbase & 1023;
        const int hh = cc0 >> 6;
        float qmul = 1.0f;
        if (tt == 0) qmul = __expf(fminf(scale_mul_log[hh], LOG100)) * LOG2E;
#pragma unroll
        for (int mt = 0; mt < 4; mt++) {
            float vals[4][4];
            float n2[4] = {0.f, 0.f, 0.f, 0.f};
#pragma unroll
            for (int nt = 0; nt < 4; nt++) {
                const int ci = cc0 + nt * 16 + c16;   // 0..1023 within qkv third
                float badd = 0.f;
                if (tt == 0) badd = q_bias[ci];
                else if (tt == 2) badd = v_bias[ci];
#pragma unroll
                for (int r = 0; r < 4; r++) {
                    float v = acc[mt][nt][r] + badd;
                    vals[nt][r] = v;
                    n2[r] += v * v;
                }
            }
            float rs[4];
            if (tt < 2) {   // L2-normalize q (with scale*log2e) and k over the 64-wide head dim
#pragma unroll
                for (int r = 0; r < 4; r++) {
                    float s = n2[r];
                    s += __shfl_xor(s, 1, 64);
                    s += __shfl_xor(s, 2, 64);
                    s += __shfl_xor(s, 4, 64);
                    s += __shfl_xor(s, 8, 64);
                    rs[r] = qmul / fmaxf(sqrtf(s), 1e-12f);
                }
            } else {
#pragma unroll
                for (int r = 0; r < 4; r++) rs[r] = 1.0f;
            }
#pragma unroll
            for (int nt = 0; nt < 4; nt++) {
                const int dd = (cc0 + nt * 16 + c16) & 63;
#pragma unroll
                for (int r = 0; r < 4; r++) {
                    const int row = m0 + wm + mt * 16 + g * 4 + r;   // b*2048 + l
                    const int bb = row >> 11, ll = row & 2047;
                    const size_t bhx = (size_t)bb * NH + hh;
                    const uint16_t val = f2bf(vals[nt][r] * rs[r]);
                    if (tt < 2) {
                        size_t addr = ((bhx * 64 + (ll >> 5)) * 4 + (dd >> 4)) * 512
                                      + ((dd >> 3) & 1) * 256 + (ll & 31) * 8 + (dd & 7);
                        if (tt == 0) qb[addr] = val; else kb[addr] = val;
                    } else {
                        size_t addr = ((bhx * 64 + (ll >> 5)) * 4 + (dd >> 5) * 2 + ((ll >> 4) & 1)) * 512
                                      + (((ll >> 3) & 1) * 32 + (dd & 31)) * 8 + (ll & 7);
                        vtb[addr] = val;
                    }
                }
            }
        }
    } else {
#pragma unroll
        for (int mt = 0; mt < 4; mt++)
#pragma unroll
            for (int nt = 0; nt < 4; nt++)
#pragma unroll
                for (int r = 0; r < 4; r++) {
                    int row = m0 + wm + mt * 16 + g * 4 + r;
                    int col = n0 + wn + nt * 16 + c16;
                    outp[(size_t)row * N + col] = acc[mt][nt][r] + b_proj[col];
                }
    }
}

// ---------------- fused cosine-sim flash attention ----------------
// grid: 512 blocks (h*32+qt); block: 4 waves, wave w = batch w, QBLK=64 (2 qg x 32 rows).
// KVBLK=32, DOUBLE-BUFFERED fragment-linear LDS: K/V pre-arranged in frag order by the
// GEMM epilogue -> gload_lds has contiguous 1KB global bursts AND lane-linear LDS
// (zero bank conflicts, R5-proven). Bias [granule][row] LDS: reads 2-way-free.
// T3-minimum pipeline, ONE barrier/iter: {ds_write bias(t+1); issue bias regs(t+2);
// issue stage(t+1); compute(t); barrier} -> the vmcnt(0) drain at the barrier lands
// after a full compute phase.
// Core: swapped mfma(K,Q) 32x32x16 (m74/m101 layout), static-max softmax,
// cvt_pk + permlane32_swap repack (m214-v22) — numerics identical to R10 (passed).
__global__ __launch_bounds__(256) void attn_kernel(
    const uint16_t* __restrict__ qfrag, const uint16_t* __restrict__ kfrag,
    const uint16_t* __restrict__ vfrag, const float* __restrict__ bias,
    uint16_t* __restrict__ ob)
{
    __shared__ __align__(16) uint16_t KsL[2 * 4 * 4 * 512];  // [buf][batch][slot][lane*8] 32 KB
    __shared__ __align__(16) uint16_t VsL[2 * 4 * 4 * 512];  // 32 KB
    __shared__ __align__(16) uint2    Bsh[2 * 8 * 64];       // [buf][granule][qrow] bf16x4, 8 KB

    const int t = threadIdx.x;
    const int w = t >> 6, lane = t & 63;       // wave index == batch index
    const int c32 = lane & 31, hi = lane >> 5;

    const int h = blockIdx.x >> 5;             // 0..15
    const int qt = blockIdx.x & 31;            // 0..31
    const int q0 = qt * 64;
    const size_t bh = (size_t)w * NH + h;

    // Q fragments: 2 qg x 4 d-slots (coalesced: frag-ordered workspace)
    bf16x8 qf[2][4];
#pragma unroll
    for (int qg = 0; qg < 2; qg++)
#pragma unroll
        for (int s = 0; s < 4; s++)
            qf[qg][s] = *(const bf16x8*)(qfrag +
                ((bh * 64 + (size_t)(qt * 2 + qg)) * 4 + s) * 512 + hi * 256 + c32 * 8);

    // wave-private K/V staging: 8 gload_lds, each 64 lanes x 16B contiguous
    auto stage = [&](int tl, int buf) {
        const uint16_t* kp = kfrag + ((bh * 64 + (size_t)tl) * 4) * 512 + lane * 8;
        const uint16_t* vp = vfrag + ((bh * 64 + (size_t)tl) * 4) * 512 + lane * 8;
#pragma unroll
        for (int s = 0; s < 4; s++)
            gload_lds16(kp + s * 512, &KsL[((buf * 4 + w) * 4 + s) * 512 + lane * 8]);
#pragma unroll
        for (int s = 0; s < 4; s++)
            gload_lds16(vp + s * 512, &VsL[((buf * 4 + w) * 4 + s) * 512 + lane * 8]);
    };

    f32x16 accO[2][2];
#pragma unroll
    for (int qg = 0; qg < 2; qg++)
#pragma unroll
        for (int db = 0; db < 2; db++)
#pragma unroll
            for (int i = 0; i < 16; i++) accO[qg][db][i] = 0.f;
    float lrun[2] = {0.f, 0.f};

    // bias cooperative load mapping: thread t -> row = t>>2 (0..63), kpart = t&3
    // global: [q0+row][k0 + kpart*8 .. +8) ; granules g0 = kpart*2, g0+1
    const int brow = t >> 2, g0 = (t & 3) * 2;
    const float* bgl = bias + ((size_t)h * SEQ + q0 + brow) * SEQ + (t & 3) * 8;

    // prologue: bias(0) + stage(0)
    float4 br0 = *(const float4*)(bgl);
    float4 br1 = *(const float4*)(bgl + 4);
    stage(0, 0);
    asm volatile("s_waitcnt vmcnt(0)" ::: "memory");
    Bsh[g0 * 64 + brow] = make_uint2(cvt_pk_bf16(br0.x * LOG2E, br0.y * LOG2E),
                                     cvt_pk_bf16(br0.z * LOG2E, br0.w * LOG2E));
    Bsh[(g0 + 1) * 64 + brow] = make_uint2(cvt_pk_bf16(br1.x * LOG2E, br1.y * LOG2E),
                                           cvt_pk_bf16(br1.z * LOG2E, br1.w * LOG2E));
    br0 = *(const float4*)(bgl + 32);
    br1 = *(const float4*)(bgl + 36);
    __syncthreads();

    for (int it = 0; it < 64; ++it) {
        const int cur = it & 1;
        if (it < 63) {
            const int nb = cur ^ 1;
            // bias(it+1): regs -> LDS (regs drained by last barrier)
            Bsh[nb * 512 + g0 * 64 + brow] =
                make_uint2(cvt_pk_bf16(br0.x * LOG2E, br0.y * LOG2E),
                           cvt_pk_bf16(br0.z * LOG2E, br0.w * LOG2E));
            Bsh[nb * 512 + (g0 + 1) * 64 + brow] =
                make_uint2(cvt_pk_bf16(br1.x * LOG2E, br1.y * LOG2E),
                           cvt_pk_bf16(br1.z * LOG2E, br1.w * LOG2E));
            // bias regs(it+2) FIRST (so their next use needs no vmcnt(0))...
            int nt2 = it + 2; if (nt2 > 63) nt2 = 63;
            br0 = *(const float4*)(bgl + nt2 * 32);
            br1 = *(const float4*)(bgl + nt2 * 32 + 4);
            // ...then the K/V DMA (in flight across the whole compute phase)
            stage(it + 1, nb);
        }

        // ---- compute tile it from buf[cur] ----
        bf16x8 kf[4], vf[4];
#pragma unroll
        for (int s = 0; s < 4; s++)
            kf[s] = *(const bf16x8*)&KsL[((cur * 4 + w) * 4 + s) * 512 + lane * 8];
#pragma unroll
        for (int s = 0; s < 4; s++)
            vf[s] = *(const bf16x8*)&VsL[((cur * 4 + w) * 4 + s) * 512 + lane * 8];

#pragma unroll
        for (int qg = 0; qg < 2; qg++) {
            // S^T = K Q^T : reg r -> k_local = (r&3)+8*(r>>2)+4*hi ; q-row = c32
            f32x16 S;
#pragma unroll
            for (int i = 0; i < 16; i++) S[i] = 0.f;
#pragma unroll
            for (int s = 0; s < 4; s++)
                S = __builtin_amdgcn_mfma_f32_32x32x16_bf16(kf[s], qf[qg][s], S, 0, 0, 0);

            // softmax (static max): p = exp2(S + bias*log2e); bias granule g = tt*2+hi
            float p[16];
            float lp = 0.f;
#pragma unroll
            for (int tt = 0; tt < 4; tt++) {
                uint2 uu = Bsh[cur * 512 + (tt * 2 + hi) * 64 + qg * 32 + c32];
                p[tt * 4 + 0] = exp2_fast(S[tt * 4 + 0] + u32lo_f(uu.x));
                p[tt * 4 + 1] = exp2_fast(S[tt * 4 + 1] + u32hi_f(uu.x));
                p[tt * 4 + 2] = exp2_fast(S[tt * 4 + 2] + u32lo_f(uu.y));
                p[tt * 4 + 3] = exp2_fast(S[tt * 4 + 3] + u32hi_f(uu.y));
                lp += (p[tt * 4 + 0] + p[tt * 4 + 1]) + (p[tt * 4 + 2] + p[tt * 4 + 3]);
            }
            lrun[qg] += lp;

            // m214 repack -> PV A-fragments (pa[0]: k 0..15, pa[1]: k 16..31)
            bf16x8 pa[2];
#pragma unroll
            for (int cp = 0; cp < 2; cp++) {
                uint32_t X0 = cvt_pk_bf16(p[8 * cp + 0], p[8 * cp + 1]);
                uint32_t X1 = cvt_pk_bf16(p[8 * cp + 2], p[8 * cp + 3]);
                uint32_t Y0 = cvt_pk_bf16(p[8 * cp + 4], p[8 * cp + 5]);
                uint32_t Y1 = cvt_pk_bf16(p[8 * cp + 6], p[8 * cp + 7]);
                p32swap(X0, Y0);
                p32swap(X1, Y1);
                union { uint32_t u[4]; bf16x8 v; } pu;
                pu.u[0] = X0; pu.u[1] = X1; pu.u[2] = Y0; pu.u[3] = Y1;
                pa[cp] = pu.v;
            }

            // O += P V : V slot jj = db*2+c holds V^T[db*32+c32][(2c+hi)*8..]
#pragma unroll
            for (int c = 0; c < 2; c++)
#pragma unroll
                for (int db = 0; db < 2; db++)
                    accO[qg][db] = __builtin_amdgcn_mfma_f32_32x32x16_bf16(
                        pa[c], vf[db * 2 + c], accO[qg][db], 0, 0, 0);
        }

        __syncthreads();   // single drain/iter: stage(it+1)+bias regs covered by compute
    }

    // finalize: row-sum reduce + redistribute, O /= l, write bf16 [B, L, H*D]
#pragma unroll
    for (int qg = 0; qg < 2; qg++) {
        float s = lrun[qg] + __shfl_xor(lrun[qg], 32, 64);
        float inv = 1.0f / s;                 // valid for q-row = c32 on all lanes
        float linv[16];
#pragma unroll
        for (int r = 0; r < 16; r++)
            linv[r] = __shfl(inv, (r & 3) + 8 * (r >> 2) + 4 * hi, 64);
#pragma unroll
        for (int r = 0; r < 16; r++) {
            int rowq = (r & 3) + 8 * (r >> 2) + 4 * hi;
            size_t rowbase = ((size_t)w * SEQ + q0 + qg * 32 + rowq) * CMOD + h * DH;
            ob[rowbase + c32]      = f2bf(accO[qg][0][r] * linv[r]);
            ob[rowbase + 32 + c32] = f2bf(accO[qg][1][r] * linv[r]);
        }
    }
}

// ---------------- launch ----------------
extern "C" void kernel_launch(void* const* d_in, const int* in_sizes, int n_in,
                              void* d_out, int out_size, void* d_ws, size_t ws_size,
                              hipStream_t stream) {
    const float* x             = (const float*)d_in[0];
    const float* attn_bias     = (const float*)d_in[1];
    const float* W_qkv         = (const float*)d_in[2];
    const float* q_bias        = (const float*)d_in[3];
    const float* v_bias        = (const float*)d_in[4];
    const float* scale_mul_log = (const float*)d_in[5];
    const float* W_proj        = (const float*)d_in[6];
    const float* b_proj        = (const float*)d_in[7];
    float* out = (float*)d_out;

    uint8_t* ws = (uint8_t*)d_ws;
    size_t off = 0;
    auto alloc = [&](size_t bytes) { uint8_t* p = ws + off; off += (bytes + 255) & ~(size_t)255; return p; };
    uint16_t* xb     = (uint16_t*)alloc((size_t)8192 * 1024 * 2);
    uint16_t* wqkvb  = (uint16_t*)alloc((size_t)3072 * 1024 * 2);
    uint16_t* wprojb = (uint16_t*)alloc((size_t)1024 * 1024 * 2);
    uint16_t* qb     = (uint16_t*)alloc((size_t)BATCH * NH * SEQ * DH * 2);
    uint16_t* kb     = (uint16_t*)alloc((size_t)BATCH * NH * SEQ * DH * 2);
    uint16_t* vtb    = (uint16_t*)alloc((size_t)BATCH * NH * SEQ * DH * 2);
    uint16_t* ob     = (uint16_t*)alloc((size_t)BATCH * SEQ * CMOD * 2);
    (void)ws_size;

    cvt_kernel<<<8192, 256, 0, stream>>>(x, xb, 8388608);
    cvt_kernel<<<3072, 256, 0, stream>>>(W_qkv, wqkvb, 3145728);
    cvt_kernel<<<1024, 256, 0, stream>>>(W_proj, wprojb, 1048576);

    dim3 g1(64, 24);
    gemm_bt_kernel<<<g1, 256, 0, stream>>>(xb, wqkvb, 8192, 3072, 1024, 0,
                                           qb, kb, vtb, q_bias, v_bias, scale_mul_log,
                                           nullptr, nullptr);

    attn_kernel<<<512, 256, 0, stream>>>(qb, kb, vtb, attn_bias, ob);

    dim3 g3(64, 8);
    gemm_bt_kernel<<<g3, 256, 0, stream>>>(ob, wprojb, 8192, 1024, 1024, 1,
                                           nullptr, nullptr, nullptr, nullptr, nullptr, nullptr,
                                           out, b_proj);
}